// Round 1
// baseline (282.002 us; speedup 1.0000x reference)
//
#include <hip/hip_runtime.h>

#define N_NODES 100000
#define N_EDGES 1600000
#define HIDDEN 256
#define CONV_OUT 128

// ---------------- kernel 1: fold W12 = W1@W2, c = b1@W2 + b2 ----------------
__global__ void k_w12(const float* __restrict__ W1, const float* __restrict__ b1,
                      const float* __restrict__ W2, const float* __restrict__ b2,
                      float* __restrict__ W12, float* __restrict__ cvec) {
    int h = threadIdx.x;  // 256 threads, one per HIDDEN row
    float a0 = 0.f, a1 = 0.f;
    for (int k = 0; k < CONV_OUT; ++k) {
        float w = W1[h * CONV_OUT + k];
        a0 += w * W2[k * 2 + 0];
        a1 += w * W2[k * 2 + 1];
    }
    W12[h * 2 + 0] = a0;
    W12[h * 2 + 1] = a1;
    if (h < 2) {
        float acc = b2[h];
        for (int k = 0; k < CONV_OUT; ++k) acc += b1[k] * W2[k * 2 + h];
        cvec[h] = acc;
    }
}

// ---------------- kernel 2: deg init to self-loop weight 1.0 ----------------
__global__ void k_deg_init(float* __restrict__ deg) {
    int i = blockIdx.x * 256 + threadIdx.x;
    if (i < N_NODES) deg[i] = 1.0f;
}

// ---------------- kernel 3: deg[dst] += w per edge --------------------------
__global__ void k_deg(const int* __restrict__ ei, const float* __restrict__ w,
                      float* __restrict__ deg) {
    int e = blockIdx.x * 256 + threadIdx.x;
    if (e < N_EDGES) atomicAdd(&deg[ei[N_EDGES + e]], w[e]);
}

// ------ kernel 4: z = x@W12 (wave/node); dinv; out-init = dinv^2*z + c ------
__global__ __launch_bounds__(256) void k_z(
        const float* __restrict__ x, const float* __restrict__ W12,
        const float* __restrict__ deg, const float* __restrict__ cvec,
        float* __restrict__ z, float* __restrict__ dinv, float* __restrict__ out) {
    int wid  = (int)((blockIdx.x * blockDim.x + threadIdx.x) >> 6);  // node id
    int lane = threadIdx.x & 63;
    if (wid >= N_NODES) return;

    const float4 xv = *(const float4*)(x + (size_t)wid * HIDDEN + lane * 4);
    float a0 = 0.f, a1 = 0.f;
#pragma unroll
    for (int j = 0; j < 4; ++j) {
        float xf = ((const float*)&xv)[j];
        a0 += xf * W12[(lane * 4 + j) * 2 + 0];
        a1 += xf * W12[(lane * 4 + j) * 2 + 1];
    }
#pragma unroll
    for (int m = 32; m >= 1; m >>= 1) {
        a0 += __shfl_xor(a0, m, 64);
        a1 += __shfl_xor(a1, m, 64);
    }
    if (lane == 0) {
        float d  = deg[wid];
        float di = d > 0.f ? rsqrtf(d) : 0.f;
        dinv[wid] = di;
        *(float2*)(z + 2 * wid) = make_float2(a0, a1);
        float nw = di * di;  // self-loop norm = dinv*1*dinv
        out[2 * wid + 0] = nw * a0 + cvec[0];
        out[2 * wid + 1] = nw * a1 + cvec[1];
    }
}

// ------ kernel 5: out[dst] += dinv[src]*w*dinv[dst] * z[src] (atomics) ------
__global__ void k_scatter(const int* __restrict__ ei, const float* __restrict__ w,
                          const float* __restrict__ dinv, const float* __restrict__ z,
                          float* __restrict__ out) {
    int e = blockIdx.x * 256 + threadIdx.x;
    if (e >= N_EDGES) return;
    int s = ei[e];
    int d = ei[N_EDGES + e];
    float nw = dinv[s] * w[e] * dinv[d];
    float2 zv = *(const float2*)(z + 2 * s);
    atomicAdd(&out[2 * d + 0], nw * zv.x);
    atomicAdd(&out[2 * d + 1], nw * zv.y);
}

extern "C" void kernel_launch(void* const* d_in, const int* in_sizes, int n_in,
                              void* d_out, int out_size, void* d_ws, size_t ws_size,
                              hipStream_t stream) {
    const float* x  = (const float*)d_in[0];
    const int*   ei = (const int*)d_in[1];     // [2, E] row-major, int32
    const float* ew = (const float*)d_in[2];
    const float* W1 = (const float*)d_in[3];
    const float* b1 = (const float*)d_in[4];
    const float* W2 = (const float*)d_in[5];
    const float* b2 = (const float*)d_in[6];
    float* out = (float*)d_out;

    // workspace layout (all 8B-aligned)
    char* ws = (char*)d_ws;
    float* deg  = (float*)(ws);                         // 400000 B
    float* dinv = (float*)(ws + 400000);                // 400000 B
    float* z    = (float*)(ws + 800000);                // 800000 B (float2/node)
    float* W12  = (float*)(ws + 1600000);               // 2048 B
    float* cvec = (float*)(ws + 1602048);               // 8 B

    k_w12<<<1, 256, 0, stream>>>(W1, b1, W2, b2, W12, cvec);
    k_deg_init<<<(N_NODES + 255) / 256, 256, 0, stream>>>(deg);
    k_deg<<<(N_EDGES + 255) / 256, 256, 0, stream>>>(ei, ew, deg);
    k_z<<<(N_NODES * 64 + 255) / 256, 256, 0, stream>>>(x, W12, deg, cvec, z, dinv, out);
    k_scatter<<<(N_EDGES + 255) / 256, 256, 0, stream>>>(ei, ew, dinv, z, out);
}

// Round 2
// 127.479 us; speedup vs baseline: 2.2121x; 2.2121x over previous
//
#include <hip/hip_runtime.h>

#define N_NODES 100000
#define N_EDGES 1600000
#define HIDDEN 256

#define BSH 9                    // bucket = dst >> 9
#define BNODES 512               // nodes per bucket
#define NB 196                   // ceil(N_NODES / 512)
#define EPB 8192                 // edges per hist/place block
#define NBLK 196                 // ceil(N_EDGES / EPB)

// ---------------- fold W12 = W1@W2, c = b1@W2 + b2 ----------------
__global__ void k_w12(const float* __restrict__ W1, const float* __restrict__ b1,
                      const float* __restrict__ W2, const float* __restrict__ b2,
                      float* __restrict__ W12, float* __restrict__ cvec) {
    int h = threadIdx.x;  // 256 threads, one per HIDDEN row
    float a0 = 0.f, a1 = 0.f;
    for (int k = 0; k < 128; ++k) {
        float w = W1[h * 128 + k];
        a0 += w * W2[k * 2 + 0];
        a1 += w * W2[k * 2 + 1];
    }
    W12[h * 2 + 0] = a0;
    W12[h * 2 + 1] = a1;
    if (h < 2) {
        float acc = b2[h];
        for (int k = 0; k < 128; ++k) acc += b1[k] * W2[k * 2 + h];
        cvec[h] = acc;
    }
}

// ---------------- per-block bucket histogram (LDS only) ----------------
__global__ __launch_bounds__(256) void k_hist(const int* __restrict__ ei,
                                              int* __restrict__ blkhist) {
    __shared__ int hist[NB];
    for (int i = threadIdx.x; i < NB; i += 256) hist[i] = 0;
    __syncthreads();
    int base = blockIdx.x * EPB;
    int end  = min(base + EPB, N_EDGES);
    for (int e = base + threadIdx.x; e < end; e += 256)
        atomicAdd(&hist[ei[N_EDGES + e] >> BSH], 1);
    __syncthreads();
    for (int i = threadIdx.x; i < NB; i += 256)
        blkhist[blockIdx.x * NB + i] = hist[i];
}

// -------- 2D scan: blkhist -> absolute per-block cursors, bucket bases --------
__global__ __launch_bounds__(256) void k_scan(int* __restrict__ blkhist,
                                              int* __restrict__ bucket_base,
                                              int* __restrict__ bucket_total) {
    __shared__ int total[NB];
    __shared__ int base_sh[NB];
    int b = threadIdx.x;
    if (b < NB) {
        int run = 0;
        for (int blk = 0; blk < NBLK; ++blk) {
            int t = blkhist[blk * NB + b];
            blkhist[blk * NB + b] = run;   // relative offset within bucket
            run += t;
        }
        total[b] = run;
    }
    __syncthreads();
    if (threadIdx.x == 0) {
        int run = 0;
        for (int i = 0; i < NB; ++i) {
            base_sh[i] = run;
            bucket_base[i]  = run;
            bucket_total[i] = total[i];
            run += total[i];
        }
    }
    __syncthreads();
    if (b < NB) {
        int bb = base_sh[b];
        for (int blk = 0; blk < NBLK; ++blk) blkhist[blk * NB + b] += bb;  // absolute
    }
}

// ---------------- place records {src, w, dstloc} into buckets ----------------
__global__ __launch_bounds__(256) void k_place(const int* __restrict__ ei,
                                               const float* __restrict__ w,
                                               const int* __restrict__ blkabs,
                                               uint4* __restrict__ rec) {
    __shared__ int cursor[NB];
    for (int i = threadIdx.x; i < NB; i += 256)
        cursor[i] = blkabs[blockIdx.x * NB + i];
    __syncthreads();
    int base = blockIdx.x * EPB;
    int end  = min(base + EPB, N_EDGES);
    for (int e = base + threadIdx.x; e < end; e += 256) {
        int d = ei[N_EDGES + e];
        int bk = d >> BSH;
        int pos = atomicAdd(&cursor[bk], 1);
        uint4 r;
        r.x = (unsigned)ei[e];                 // src
        r.y = __float_as_uint(w[e]);           // edge weight
        r.z = (unsigned)(d & (BNODES - 1));    // dst local id
        r.w = 0;
        rec[pos] = r;
    }
}

// ---------------- deg per bucket via LDS accumulation ----------------
__global__ __launch_bounds__(512) void k_deg2(const uint4* __restrict__ rec,
                                              const int* __restrict__ bucket_base,
                                              const int* __restrict__ bucket_total,
                                              float* __restrict__ deg) {
    __shared__ float acc[BNODES];
    for (int i = threadIdx.x; i < BNODES; i += 512) acc[i] = 1.0f;  // self-loop weight
    __syncthreads();
    int b = blockIdx.x, s = bucket_base[b], n = bucket_total[b];
    for (int i = threadIdx.x; i < n; i += 512) {
        uint4 r = rec[s + i];
        atomicAdd(&acc[r.z], __uint_as_float(r.y));
    }
    __syncthreads();
    for (int i = threadIdx.x; i < BNODES; i += 512) {
        int node = b * BNODES + i;
        if (node < N_NODES) deg[node] = acc[i];
    }
}

// ------ z = x@W12 (wave/node); dinv; out-init = dinv^2*z + c (self-loop) ------
__global__ __launch_bounds__(256) void k_z(
        const float* __restrict__ x, const float* __restrict__ W12,
        const float* __restrict__ deg, const float* __restrict__ cvec,
        float* __restrict__ z, float* __restrict__ dinv, float* __restrict__ out) {
    int wid  = (int)((blockIdx.x * blockDim.x + threadIdx.x) >> 6);  // node id
    int lane = threadIdx.x & 63;
    if (wid >= N_NODES) return;

    const float4 xv = *(const float4*)(x + (size_t)wid * HIDDEN + lane * 4);
    float a0 = 0.f, a1 = 0.f;
#pragma unroll
    for (int j = 0; j < 4; ++j) {
        float xf = ((const float*)&xv)[j];
        a0 += xf * W12[(lane * 4 + j) * 2 + 0];
        a1 += xf * W12[(lane * 4 + j) * 2 + 1];
    }
#pragma unroll
    for (int m = 32; m >= 1; m >>= 1) {
        a0 += __shfl_xor(a0, m, 64);
        a1 += __shfl_xor(a1, m, 64);
    }
    if (lane == 0) {
        float d  = deg[wid];
        float di = d > 0.f ? rsqrtf(d) : 0.f;
        dinv[wid] = di;
        *(float2*)(z + 2 * wid) = make_float2(a0, a1);
        float nw = di * di;
        out[2 * wid + 0] = nw * a0 + cvec[0];
        out[2 * wid + 1] = nw * a1 + cvec[1];
    }
}

// ------ gather per bucket: out[dst] += dinv[src]*w*dinv[dst]*z[src] ------
__global__ __launch_bounds__(512) void k_gather(const uint4* __restrict__ rec,
                                                const int* __restrict__ bucket_base,
                                                const int* __restrict__ bucket_total,
                                                const float* __restrict__ dinv,
                                                const float* __restrict__ z,
                                                float* __restrict__ out) {
    __shared__ float accx[BNODES], accy[BNODES], dloc[BNODES];
    int b = blockIdx.x;
    for (int i = threadIdx.x; i < BNODES; i += 512) {
        accx[i] = 0.f; accy[i] = 0.f;
        int node = b * BNODES + i;
        dloc[i] = (node < N_NODES) ? dinv[node] : 0.f;
    }
    __syncthreads();
    int s = bucket_base[b], n = bucket_total[b];
    for (int i = threadIdx.x; i < n; i += 512) {
        uint4 r = rec[s + i];
        int src = (int)r.x;
        float nw = dinv[src] * __uint_as_float(r.y) * dloc[r.z];
        float2 zv = *(const float2*)(z + 2 * src);
        atomicAdd(&accx[r.z], nw * zv.x);
        atomicAdd(&accy[r.z], nw * zv.y);
    }
    __syncthreads();
    for (int i = threadIdx.x; i < BNODES; i += 512) {
        int node = b * BNODES + i;
        if (node < N_NODES) {
            out[2 * node + 0] += accx[i];
            out[2 * node + 1] += accy[i];
        }
    }
}

extern "C" void kernel_launch(void* const* d_in, const int* in_sizes, int n_in,
                              void* d_out, int out_size, void* d_ws, size_t ws_size,
                              hipStream_t stream) {
    const float* x  = (const float*)d_in[0];
    const int*   ei = (const int*)d_in[1];     // [2, E] row-major, int32
    const float* ew = (const float*)d_in[2];
    const float* W1 = (const float*)d_in[3];
    const float* b1 = (const float*)d_in[4];
    const float* W2 = (const float*)d_in[5];
    const float* b2 = (const float*)d_in[6];
    float* out = (float*)d_out;

    // workspace layout
    char* ws = (char*)d_ws;
    uint4* rec        = (uint4*)(ws);                        // 25,600,000 B
    size_t off = (size_t)N_EDGES * 16;
    int* blkhist      = (int*)(ws + off);  off += (size_t)NBLK * NB * 4;   // 153,664
    int* bucket_base  = (int*)(ws + off);  off += NB * 4;
    int* bucket_total = (int*)(ws + off);  off += NB * 4;
    float* deg        = (float*)(ws + off); off += N_NODES * 4;
    float* dinv       = (float*)(ws + off); off += N_NODES * 4;
    float* z          = (float*)(ws + off); off += (size_t)N_NODES * 8;
    float* W12        = (float*)(ws + off); off += HIDDEN * 2 * 4;
    float* cvec       = (float*)(ws + off); off += 8;

    k_w12  <<<1, 256, 0, stream>>>(W1, b1, W2, b2, W12, cvec);
    k_hist <<<NBLK, 256, 0, stream>>>(ei, blkhist);
    k_scan <<<1, 256, 0, stream>>>(blkhist, bucket_base, bucket_total);
    k_place<<<NBLK, 256, 0, stream>>>(ei, ew, blkhist, rec);
    k_deg2 <<<NB, 512, 0, stream>>>(rec, bucket_base, bucket_total, deg);
    k_z    <<<(N_NODES * 64 + 255) / 256, 256, 0, stream>>>(x, W12, deg, cvec, z, dinv, out);
    k_gather<<<NB, 512, 0, stream>>>(rec, bucket_base, bucket_total, dinv, z, out);
}

// Round 3
// 99.275 us; speedup vs baseline: 2.8406x; 1.2841x over previous
//
#include <hip/hip_runtime.h>

#define N_NODES 100000
#define N_EDGES 1600000
#define HIDDEN 256

#define BSH 8                    // bucket = dst >> 8
#define BNODES 256               // nodes per bucket
#define NB 391                   // ceil(N_NODES / 256)
#define CAP 5120                 // records per bucket region (mean 4092, sigma 64)
#define EPB 8000                 // edges per place block
#define NBLK 200                 // 200 * 8000 = 1.6M exactly

// record: uint2 { src | (dstloc << 17), float_bits(w) }

// ---- place: LDS hist -> chunk reservation (int atomics) -> packed records ----
// block NBLK additionally folds W12 = W1@W2, cvec = b1@W2 + b2.
__global__ __launch_bounds__(256) void k_place2(
        const int* __restrict__ ei, const float* __restrict__ w,
        const float* __restrict__ W1, const float* __restrict__ b1,
        const float* __restrict__ W2, const float* __restrict__ b2,
        int* __restrict__ gcur, uint2* __restrict__ rec,
        float* __restrict__ W12, float* __restrict__ cvec) {
    if (blockIdx.x == NBLK) {            // ---- W-fold block ----
        int h = threadIdx.x;
        float a0 = 0.f, a1 = 0.f;
        for (int k = 0; k < 128; ++k) {
            float v = W1[h * 128 + k];
            a0 += v * W2[2 * k + 0];
            a1 += v * W2[2 * k + 1];
        }
        W12[2 * h + 0] = a0;
        W12[2 * h + 1] = a1;
        if (h < 2) {
            float acc = b2[h];
            for (int k = 0; k < 128; ++k) acc += b1[k] * W2[2 * k + h];
            cvec[h] = acc;
        }
        return;
    }
    __shared__ int hist[NB];
    __shared__ int cursor[NB];
    for (int i = threadIdx.x; i < NB; i += 256) hist[i] = 0;
    __syncthreads();
    int base = blockIdx.x * EPB;
    for (int e = base + threadIdx.x; e < base + EPB; e += 256)
        atomicAdd(&hist[((unsigned)ei[N_EDGES + e]) >> BSH], 1);
    __syncthreads();
    for (int i = threadIdx.x; i < NB; i += 256) {
        int c = hist[i];
        int pos = c ? atomicAdd(&gcur[i], c) : 0;  // reserve contiguous chunk
        cursor[i] = i * CAP + pos;
    }
    __syncthreads();
    for (int e = base + threadIdx.x; e < base + EPB; e += 256) {
        int d = ei[N_EDGES + e];
        int s = ei[e];
        int bk = ((unsigned)d) >> BSH;
        int pos = atomicAdd(&cursor[bk], 1);
        rec[pos] = make_uint2((unsigned)s | ((unsigned)(d & (BNODES - 1)) << 17),
                              __float_as_uint(w[e]));
    }
}

// ---- deg per bucket (LDS), write dinv = rsqrt(deg) directly ----
__global__ __launch_bounds__(256) void k_deg2(const uint2* __restrict__ rec,
                                              const int* __restrict__ gcur,
                                              float* __restrict__ dinv) {
    __shared__ float acc[BNODES];
    for (int i = threadIdx.x; i < BNODES; i += 256) acc[i] = 1.0f;  // self-loop
    __syncthreads();
    int b = blockIdx.x, n = gcur[b];
    const uint2* r = rec + (size_t)b * CAP;
    for (int i = threadIdx.x; i < n; i += 256) {
        uint2 q = r[i];
        atomicAdd(&acc[q.x >> 17], __uint_as_float(q.y));
    }
    __syncthreads();
    for (int i = threadIdx.x; i < BNODES; i += 256) {
        int node = b * BNODES + i;
        if (node < N_NODES) dinv[node] = rsqrtf(acc[i]);  // deg >= 1 always
    }
}

// ---- z = x @ W12 : one wave per node, float4 coalesced, shuffle reduce ----
__global__ __launch_bounds__(256) void k_z(const float* __restrict__ x,
                                           const float* __restrict__ W12,
                                           float* __restrict__ z) {
    int wid  = (int)((blockIdx.x * blockDim.x + threadIdx.x) >> 6);
    int lane = threadIdx.x & 63;
    if (wid >= N_NODES) return;
    const float4 xv = *(const float4*)(x + (size_t)wid * HIDDEN + lane * 4);
    float a0 = 0.f, a1 = 0.f;
#pragma unroll
    for (int j = 0; j < 4; ++j) {
        float xf = ((const float*)&xv)[j];
        a0 += xf * W12[(lane * 4 + j) * 2 + 0];
        a1 += xf * W12[(lane * 4 + j) * 2 + 1];
    }
#pragma unroll
    for (int m = 32; m >= 1; m >>= 1) {
        a0 += __shfl_xor(a0, m, 64);
        a1 += __shfl_xor(a1, m, 64);
    }
    if (lane == 0) ((float2*)z)[wid] = make_float2(a0, a1);
}

// ---- gather per bucket; flush fuses self-loop + bias; out written once ----
__global__ __launch_bounds__(256) void k_gather(const uint2* __restrict__ rec,
                                                const int* __restrict__ gcur,
                                                const float* __restrict__ dinv,
                                                const float* __restrict__ z,
                                                const float* __restrict__ cvec,
                                                float* __restrict__ out) {
    __shared__ float accx[BNODES], accy[BNODES];
    for (int i = threadIdx.x; i < BNODES; i += 256) { accx[i] = 0.f; accy[i] = 0.f; }
    __syncthreads();
    int b = blockIdx.x, n = gcur[b];
    const uint2* r = rec + (size_t)b * CAP;
    for (int i = threadIdx.x; i < n; i += 256) {
        uint2 q = r[i];
        int src = (int)(q.x & 0x1FFFFu);
        float nw = dinv[src] * __uint_as_float(q.y);   // dinv[dst] factored to flush
        float2 zv = ((const float2*)z)[src];
        int dl = (int)(q.x >> 17);
        atomicAdd(&accx[dl], nw * zv.x);
        atomicAdd(&accy[dl], nw * zv.y);
    }
    __syncthreads();
    float c0 = cvec[0], c1 = cvec[1];
    for (int i = threadIdx.x; i < BNODES; i += 256) {
        int node = b * BNODES + i;
        if (node < N_NODES) {
            float di = dinv[node];
            float2 zv = ((const float2*)z)[node];
            ((float2*)out)[node] = make_float2(di * accx[i] + di * di * zv.x + c0,
                                               di * accy[i] + di * di * zv.y + c1);
        }
    }
}

extern "C" void kernel_launch(void* const* d_in, const int* in_sizes, int n_in,
                              void* d_out, int out_size, void* d_ws, size_t ws_size,
                              hipStream_t stream) {
    const float* x  = (const float*)d_in[0];
    const int*   ei = (const int*)d_in[1];     // [2, E] row-major
    const float* ew = (const float*)d_in[2];
    const float* W1 = (const float*)d_in[3];
    const float* b1 = (const float*)d_in[4];
    const float* W2 = (const float*)d_in[5];
    const float* b2 = (const float*)d_in[6];
    float* out = (float*)d_out;

    // workspace layout (8B-aligned throughout)
    char* ws = (char*)d_ws;
    uint2* rec  = (uint2*)ws;                    size_t off = (size_t)NB * CAP * 8;  // 16,015,360
    int*   gcur = (int*)(ws + off);              off += 1568;                        // NB*4 rounded
    float* dinv = (float*)(ws + off);            off += (size_t)N_NODES * 4;
    float* z    = (float*)(ws + off);            off += (size_t)N_NODES * 8;
    float* W12  = (float*)(ws + off);            off += HIDDEN * 2 * 4;
    float* cvec = (float*)(ws + off);            off += 8;

    hipMemsetAsync(gcur, 0, NB * sizeof(int), stream);
    k_place2<<<NBLK + 1, 256, 0, stream>>>(ei, ew, W1, b1, W2, b2, gcur, rec, W12, cvec);
    k_deg2  <<<NB, 256, 0, stream>>>(rec, gcur, dinv);
    k_z     <<<(N_NODES * 64 + 255) / 256, 256, 0, stream>>>(x, W12, z);
    k_gather<<<NB, 256, 0, stream>>>(rec, gcur, dinv, z, cvec, out);
}